// Round 1
// baseline (81532.410 us; speedup 1.0000x reference)
//
#include <hip/hip_runtime.h>

#define B_ 128
#define T_ 1024
#define H_ 400
#define G4H 1600
#define NBLK 256
#define NTHR 512
#define G0N 86
#define G1N 169
#define PHASES 1026

// shared memory layout (bytes)
#define SHS_BYTES (B_ * 32 * 16)               // 65536: staged input chunk, 128 rows x 32 float4
#define SW_OFF    SHS_BYTES
#define SW_FLOATS 9792                          // max(20*464, 12*816)
#define SGS_OFF   (SW_OFF + SW_FLOATS * 4)      // gate staging 128 x 20 floats
#define SCST_OFF  (SGS_OFF + 2560 * 4)          // cell state 128 x 5 floats
#define SMEM_BYTES (SCST_OFF + 640 * 4)         // 117504 total

__device__ __forceinline__ float sigmf(float x) { return 1.0f / (1.0f + __expf(-x)); }

// Two-level (XCD-aware) device-wide barrier. 256 blocks, bid&7 -> 32 blocks per slot.
__device__ __forceinline__ void grid_barrier(unsigned* bar, int p, int bid) {
  __threadfence();   // make this block's global writes agent-visible
  __syncthreads();
  if (threadIdx.x == 0) {
    const int x = bid & 7;
    unsigned* lc  = bar + x * 32;
    unsigned* gc  = bar + 256;
    unsigned* rel = bar + 288 + x * 32;
    const unsigned tgt = (unsigned)(p + 1);
    unsigned old = __hip_atomic_fetch_add(lc, 1u, __ATOMIC_ACQ_REL, __HIP_MEMORY_SCOPE_AGENT);
    if (old == tgt * 32u - 1u) {
      unsigned og = __hip_atomic_fetch_add(gc, 1u, __ATOMIC_ACQ_REL, __HIP_MEMORY_SCOPE_AGENT);
      if (og == tgt * 8u - 1u) {
        #pragma unroll
        for (int i = 0; i < 8; ++i)
          __hip_atomic_store(bar + 288 + i * 32, tgt, __ATOMIC_RELEASE, __HIP_MEMORY_SCOPE_AGENT);
      }
    }
    while (__hip_atomic_load(rel, __ATOMIC_RELAXED, __HIP_MEMORY_SCOPE_AGENT) < tgt)
      __builtin_amdgcn_s_sleep(2);
    (void)__hip_atomic_load(rel, __ATOMIC_ACQUIRE, __HIP_MEMORY_SCOPE_AGENT);
  }
  __syncthreads();
}

// ---------------- Layer 0: gates = [h0 ; x] @ [Wh0 ; Wx0], K = 456 ----------------
template<int U>
__device__ void run_l0(int bid, int u0,
    const float* __restrict__ xr, const float* __restrict__ xc,
    const float* __restrict__ Wx0, const float* __restrict__ Wh0, const float* __restrict__ b0,
    float* __restrict__ h0buf, unsigned* bar, unsigned char* smem)
{
  const int tid = threadIdx.x;
  float4* s_hs  = (float4*)smem;
  float*  s_w   = (float*)(smem + SW_OFF);
  float*  s_gs  = (float*)(smem + SGS_OFF);
  float*  s_cst = (float*)(smem + SCST_OFF);
  const int C = 4 * U;

  // stage weight slice once: unified K axis [Wh0 rows(400); Wx0 rows(56)]
  for (int idx = tid; idx < 456 * C; idx += NTHR) {
    int k = idx / C, c = idx - k * C;
    int g = c / U, ul = c - g * U;
    int gc = g * H_ + u0 + ul;
    float v = (k < 400) ? Wh0[k * G4H + gc] : Wx0[(k - 400) * G4H + gc];
    s_w[c * 464 + k] = v;
  }
  for (int idx = tid; idx < B_ * U; idx += NTHR) s_cst[idx] = 0.f;
  __syncthreads();

  const int ks = tid & 15;          // k-split 16
  const int g  = (tid >> 4) & 3;    // gate
  const int bo = tid >> 6;          // batch group (0..7), = wave id

  for (int p = 0; p < PHASES; ++p) {
    if (p < 1024) {
      const int t = p;
      const float* h0prev = h0buf + ((p + 1) & 1) * (B_ * H_);
      float* h0new = h0buf + (p & 1) * (B_ * H_);

      float acc[16][U];
      #pragma unroll
      for (int i = 0; i < 16; ++i)
        #pragma unroll
        for (int j = 0; j < U; ++j) acc[i][j] = 0.f;

      for (int ch = 0; ch < 4; ++ch) {
        const int k0 = ch * 128;
        const int nq = (ch < 3) ? 32 : 18;   // last chunk: k 384..456 (16 h + 40 xr + 16 xc)
        for (int idx = tid; idx < B_ * nq; idx += NTHR) {
          int b, q;
          if (ch < 3) { b = idx >> 5; q = idx & 31; }
          else        { b = idx / 18; q = idx - b * 18; }
          int k = k0 + 4 * q;
          float4 v;
          if (k < 400)       v = *reinterpret_cast<const float4*>(h0prev + b * H_ + k);
          else if (k < 440)  v = *reinterpret_cast<const float4*>(xr + (b * T_ + t) * 40 + (k - 400));
          else               v = *reinterpret_cast<const float4*>(xc + (b * T_ + t) * 16 + (k - 440));
          s_hs[b * 32 + q] = v;
        }
        __syncthreads();
        for (int i = ks; i < nq; i += 16) {
          float4 wv[U];
          #pragma unroll
          for (int j = 0; j < U; ++j)
            wv[j] = *reinterpret_cast<const float4*>(s_w + (g * U + j) * 464 + k0 + 4 * i);
          #pragma unroll
          for (int sb = 0; sb < 16; ++sb) {
            float4 hv = s_hs[(bo * 16 + sb) * 32 + i];
            #pragma unroll
            for (int j = 0; j < U; ++j) {
              acc[sb][j] = fmaf(hv.x, wv[j].x, acc[sb][j]);
              acc[sb][j] = fmaf(hv.y, wv[j].y, acc[sb][j]);
              acc[sb][j] = fmaf(hv.z, wv[j].z, acc[sb][j]);
              acc[sb][j] = fmaf(hv.w, wv[j].w, acc[sb][j]);
            }
          }
        }
        __syncthreads();
      }
      // reduce over the 16 k-split lanes
      #pragma unroll
      for (int sb = 0; sb < 16; ++sb)
        #pragma unroll
        for (int j = 0; j < U; ++j) {
          float v = acc[sb][j];
          v += __shfl_xor(v, 1);
          v += __shfl_xor(v, 2);
          v += __shfl_xor(v, 4);
          v += __shfl_xor(v, 8);
          acc[sb][j] = v;
        }
      #pragma unroll
      for (int sb = 0; sb < 16; ++sb) {
        if (ks == sb) {
          #pragma unroll
          for (int j = 0; j < U; ++j)
            s_gs[(bo * 16 + sb) * 20 + g * U + j] = acc[sb][j];
        }
      }
      __syncthreads();
      // LSTM cell update for this block's hidden units
      for (int idx = tid; idx < B_ * U; idx += NTHR) {
        int b = idx / U; int ul = idx - b * U;
        int u = u0 + ul;
        float gi = s_gs[b * 20 + 0 * U + ul] + b0[0 * H_ + u];
        float gf = s_gs[b * 20 + 1 * U + ul] + b0[1 * H_ + u];
        float gg = s_gs[b * 20 + 2 * U + ul] + b0[2 * H_ + u];
        float go = s_gs[b * 20 + 3 * U + ul] + b0[3 * H_ + u];
        float iv = sigmf(gi), fv = sigmf(gf), gv = tanhf(gg), ov = sigmf(go);
        float cn = fv * s_cst[idx] + iv * gv;
        s_cst[idx] = cn;
        h0new[b * H_ + u] = ov * tanhf(cn);
      }
    }
    if (p < PHASES - 1) grid_barrier(bar, p, bid);
  }
}

// ---------------- Layer 1: gates = [h0 ; h1] @ [Wx1 ; Wh1], K = 800 ----------------
template<int U>
__device__ void run_l1(int bid, int u0,
    const float* __restrict__ Wx1, const float* __restrict__ Wh1, const float* __restrict__ b1,
    const float* __restrict__ h0buf, float* __restrict__ h1buf,
    unsigned* bar, unsigned char* smem)
{
  const int tid = threadIdx.x;
  float4* s_hs  = (float4*)smem;
  float*  s_w   = (float*)(smem + SW_OFF);
  float*  s_gs  = (float*)(smem + SGS_OFF);
  float*  s_cst = (float*)(smem + SCST_OFF);
  const int C = 4 * U;
  constexpr int CPT = 2 * U;

  for (int idx = tid; idx < 800 * C; idx += NTHR) {
    int k = idx / C, c = idx - k * C;
    int g = c / U, ul = c - g * U;
    int gc = g * H_ + u0 + ul;
    float v = (k < 400) ? Wx1[k * G4H + gc] : Wh1[(k - 400) * G4H + gc];
    s_w[c * 816 + k] = v;
  }
  for (int idx = tid; idx < B_ * U; idx += NTHR) s_cst[idx] = 0.f;
  __syncthreads();

  const int ks = tid & 31;          // k-split 32
  const int cg = (tid >> 5) & 1;    // column group
  const int bo = tid >> 6;          // batch group

  for (int p = 0; p < PHASES; ++p) {
    if (p >= 1 && p < 1025) {
      const float* h0prev = h0buf + ((p + 1) & 1) * (B_ * H_);   // h0(p-1)
      const float* h1prev = h1buf + (p & 1) * (B_ * H_);         // h1(p-2)
      float* h1new = h1buf + ((p + 1) & 1) * (B_ * H_);          // h1(p-1)

      float acc[16][CPT];
      #pragma unroll
      for (int i = 0; i < 16; ++i)
        #pragma unroll
        for (int j = 0; j < CPT; ++j) acc[i][j] = 0.f;

      for (int ch = 0; ch < 7; ++ch) {
        const int k0 = ch * 128;
        const int nq = (ch < 6) ? 32 : 8;   // 6*128 + 32 = 800
        for (int idx = tid; idx < B_ * nq; idx += NTHR) {
          int b, q;
          if (ch < 6) { b = idx >> 5; q = idx & 31; }
          else        { b = idx >> 3; q = idx & 7; }
          int k = k0 + 4 * q;
          float4 v;
          if (k < 400) v = *reinterpret_cast<const float4*>(h0prev + b * H_ + k);
          else         v = *reinterpret_cast<const float4*>(h1prev + b * H_ + (k - 400));
          s_hs[b * 32 + q] = v;
        }
        __syncthreads();
        for (int i = ks; i < nq; i += 32) {
          float4 wv[CPT];
          #pragma unroll
          for (int j = 0; j < CPT; ++j)
            wv[j] = *reinterpret_cast<const float4*>(s_w + (cg * CPT + j) * 816 + k0 + 4 * i);
          #pragma unroll
          for (int sb = 0; sb < 16; ++sb) {
            float4 hv = s_hs[(bo * 16 + sb) * 32 + i];
            #pragma unroll
            for (int j = 0; j < CPT; ++j) {
              acc[sb][j] = fmaf(hv.x, wv[j].x, acc[sb][j]);
              acc[sb][j] = fmaf(hv.y, wv[j].y, acc[sb][j]);
              acc[sb][j] = fmaf(hv.z, wv[j].z, acc[sb][j]);
              acc[sb][j] = fmaf(hv.w, wv[j].w, acc[sb][j]);
            }
          }
        }
        __syncthreads();
      }
      #pragma unroll
      for (int sb = 0; sb < 16; ++sb)
        #pragma unroll
        for (int j = 0; j < CPT; ++j) {
          float v = acc[sb][j];
          v += __shfl_xor(v, 1);
          v += __shfl_xor(v, 2);
          v += __shfl_xor(v, 4);
          v += __shfl_xor(v, 8);
          v += __shfl_xor(v, 16);
          acc[sb][j] = v;
        }
      #pragma unroll
      for (int sb = 0; sb < 16; ++sb) {
        if (ks == sb) {
          #pragma unroll
          for (int j = 0; j < CPT; ++j)
            s_gs[(bo * 16 + sb) * 20 + cg * CPT + j] = acc[sb][j];
        }
      }
      __syncthreads();
      for (int idx = tid; idx < B_ * U; idx += NTHR) {
        int b = idx / U; int ul = idx - b * U;
        int u = u0 + ul;
        float gi = s_gs[b * 20 + 0 * U + ul] + b1[0 * H_ + u];
        float gf = s_gs[b * 20 + 1 * U + ul] + b1[1 * H_ + u];
        float gg = s_gs[b * 20 + 2 * U + ul] + b1[2 * H_ + u];
        float go = s_gs[b * 20 + 3 * U + ul] + b1[3 * H_ + u];
        float iv = sigmf(gi), fv = sigmf(gf), gv = tanhf(gg), ov = sigmf(go);
        float cn = fv * s_cst[idx] + iv * gv;
        s_cst[idx] = cn;
        h1new[b * H_ + u] = ov * tanhf(cn);
      }
    }
    if (p < PHASES - 1) grid_barrier(bar, p, bid);
  }
}

// ---------------- Dense head: out(t) = h1(t) @ Wd + bd ----------------
__device__ void run_dense(int bid, const float* __restrict__ Wd, const float* __restrict__ bd,
                          const float* __restrict__ h1buf, float* __restrict__ out,
                          unsigned* bar, unsigned char* smem)
{
  const int tid = threadIdx.x;
  float* s_wd = (float*)(smem + SW_OFF);
  for (int idx = tid; idx < 1600; idx += NTHR) s_wd[idx] = Wd[idx];
  __syncthreads();
  const int b = tid >> 2, f = tid & 3;
  const float bdv = bd[f];
  for (int p = 0; p < PHASES; ++p) {
    if (p >= 2) {
      const int t = p - 2;
      const float* h1t = h1buf + (p & 1) * (B_ * H_);   // h1(p-2)
      float acc = 0.f;
      for (int k4 = 0; k4 < 100; ++k4) {
        float4 hv = *reinterpret_cast<const float4*>(h1t + b * H_ + 4 * k4);
        acc = fmaf(hv.x, s_wd[(4 * k4 + 0) * 4 + f], acc);
        acc = fmaf(hv.y, s_wd[(4 * k4 + 1) * 4 + f], acc);
        acc = fmaf(hv.z, s_wd[(4 * k4 + 2) * 4 + f], acc);
        acc = fmaf(hv.w, s_wd[(4 * k4 + 3) * 4 + f], acc);
      }
      out[(b * T_ + t) * 4 + f] = acc + bdv;
    }
    if (p < PHASES - 1) grid_barrier(bar, p, bid);
  }
}

__global__ __launch_bounds__(NTHR, 2) void rnn_kernel(
    const float* __restrict__ xr, const float* __restrict__ xc,
    const float* __restrict__ Wx0, const float* __restrict__ Wh0, const float* __restrict__ b0,
    const float* __restrict__ Wx1, const float* __restrict__ Wh1, const float* __restrict__ b1,
    const float* __restrict__ Wd, const float* __restrict__ bd,
    float* __restrict__ out, float* ws)
{
  __shared__ __align__(16) unsigned char smem[SMEM_BYTES];
  const int bid = blockIdx.x;
  float* h0buf = ws;                       // [2][128][400]
  float* h1buf = ws + 2 * B_ * H_;         // [2][128][400]
  unsigned* bar = (unsigned*)(ws + 4 * B_ * H_);
  if (bid < G0N) {
    int u0 = bid * H_ / G0N, u1 = (bid + 1) * H_ / G0N;
    if (u1 - u0 == 5) run_l0<5>(bid, u0, xr, xc, Wx0, Wh0, b0, h0buf, bar, smem);
    else              run_l0<4>(bid, u0, xr, xc, Wx0, Wh0, b0, h0buf, bar, smem);
  } else if (bid < G0N + G1N) {
    int j = bid - G0N;
    int u0 = j * H_ / G1N, u1 = (j + 1) * H_ / G1N;
    if (u1 - u0 == 3) run_l1<3>(bid, u0, Wx1, Wh1, b1, h0buf, h1buf, bar, smem);
    else              run_l1<2>(bid, u0, Wx1, Wh1, b1, h0buf, h1buf, bar, smem);
  } else {
    run_dense(bid, Wd, bd, h1buf, out, bar, smem);
  }
}

extern "C" void kernel_launch(void* const* d_in, const int* in_sizes, int n_in,
                              void* d_out, int out_size, void* d_ws, size_t ws_size,
                              hipStream_t stream) {
  const float* xr  = (const float*)d_in[0];
  const float* xc  = (const float*)d_in[1];
  const float* Wx0 = (const float*)d_in[2];
  const float* Wh0 = (const float*)d_in[3];
  const float* b0  = (const float*)d_in[4];
  const float* Wx1 = (const float*)d_in[5];
  const float* Wh1 = (const float*)d_in[6];
  const float* b1  = (const float*)d_in[7];
  const float* Wd  = (const float*)d_in[8];
  const float* bd  = (const float*)d_in[9];
  float* out = (float*)d_out;
  float* ws  = (float*)d_ws;

  // zero h-state double buffers (4*128*400 floats) + barrier area (544 u32)
  hipMemsetAsync(d_ws, 0, (4 * B_ * H_ + 544) * sizeof(float), stream);
  hipLaunchKernelGGL(rnn_kernel, dim3(NBLK), dim3(NTHR), 0, stream,
                     xr, xc, Wx0, Wh0, b0, Wx1, Wh1, b1, Wd, bd, out, ws);
}

// Round 2
// 61587.482 us; speedup vs baseline: 1.3238x; 1.3238x over previous
//
#include <hip/hip_runtime.h>

#define B_ 128
#define T_ 1024
#define H_ 400
#define G4H 1600
#define NBLK 256
#define NTHR 512
#define G0N 86
#define G1N 169
#define SL (B_ * H_)   // floats per h slot

// shared memory layout (bytes)
#define SHS_BYTES (B_ * 128 * 4)               // 65536: staged chunk, 128 rows x 128 floats
#define SW_OFF    SHS_BYTES
#define SW_FLOATS 9792                          // max(20*464, 12*816)
#define SGS_OFF   (SW_OFF + SW_FLOATS * 4)      // gate staging 128 x 20 floats
#define SCST_OFF  (SGS_OFF + 2560 * 4)          // cell state 128 x 5 floats
#define SMEM_BYTES (SCST_OFF + 640 * 4)         // 117504 total

#define SCOPE __HIP_MEMORY_SCOPE_AGENT

__device__ __forceinline__ float sigmf(float x) { return 1.0f / (1.0f + __expf(-x)); }
__device__ __forceinline__ float ald(const float* p) {
  return __hip_atomic_load(p, __ATOMIC_RELAXED, SCOPE);   // sc1: bypass L1/L2, read LLC
}
__device__ __forceinline__ void ast(float* p, float v) {
  __hip_atomic_store(p, v, __ATOMIC_RELAXED, SCOPE);      // write-through to LLC
}
__device__ __forceinline__ void waitflag(int* f, int tgt) {
  while (__hip_atomic_load(f, __ATOMIC_RELAXED, SCOPE) < tgt)
    __builtin_amdgcn_s_sleep(4);
}
// all waves drain their h-stores to the LLC, then one lane bumps the counter
__device__ __forceinline__ void publish(int* f) {
  asm volatile("s_waitcnt vmcnt(0)" ::: "memory");
  __syncthreads();
  if (threadIdx.x == 0) __hip_atomic_fetch_add(f, 1, __ATOMIC_RELAXED, SCOPE);
}

// ---------------- Layer 0: gates(s) = [h0(s-1) ; x(s)] @ [Wh0 ; Wx0], K = 456 ----------------
template<int U>
__device__ void run_l0(int u0,
    const float* __restrict__ xr, const float* __restrict__ xc,
    const float* __restrict__ Wx0, const float* __restrict__ Wh0, const float* __restrict__ b0,
    float* __restrict__ h0buf, int* flags0, int* flags1, unsigned char* smem)
{
  const int tid = threadIdx.x;
  float*  s_hsf = (float*)smem;
  float*  s_w   = (float*)(smem + SW_OFF);
  float*  s_gs  = (float*)(smem + SGS_OFF);
  float*  s_cst = (float*)(smem + SCST_OFF);
  const int C = 4 * U;

  // stage weight slice once: unified K axis [Wh0 rows(400); Wx0 rows(56)]
  for (int idx = tid; idx < 456 * C; idx += NTHR) {
    int k = idx / C, c = idx - k * C;
    int g = c / U, ul = c - g * U;
    int gc = g * H_ + u0 + ul;
    float v = (k < 400) ? Wh0[k * G4H + gc] : Wx0[(k - 400) * G4H + gc];
    s_w[c * 464 + k] = v;
  }
  for (int idx = tid; idx < B_ * U; idx += NTHR) s_cst[idx] = 0.f;
  __syncthreads();

  const int ks = tid & 15;          // k-split 16
  const int g  = (tid >> 4) & 3;    // gate
  const int bo = tid >> 6;          // batch group (0..7) = wave id

  for (int s = 0; s < T_; ++s) {
    const float* h0prev = h0buf + ((s - 1) & 3) * SL;
    float*       h0new  = h0buf + (s & 3) * SL;

    if (tid == 0  && s >= 1) waitflag(flags0 + s - 1, G0N);  // full h0(s-1) ready
    if (tid == 64 && s >= 4) waitflag(flags1 + s - 4, G1N);  // slot s&3 free (L1 done with h0(s-4))
    __syncthreads();

    float acc[16][U];
    #pragma unroll
    for (int i = 0; i < 16; ++i)
      #pragma unroll
      for (int j = 0; j < U; ++j) acc[i][j] = 0.f;

    for (int ch = 0; ch < 4; ++ch) {
      const int k0 = ch * 128;
      if (ch < 3) {
        for (int idx = tid; idx < B_ * 128; idx += NTHR) {
          int b = idx >> 7, kk = idx & 127;
          s_hsf[idx] = ald(h0prev + b * H_ + k0 + kk);
        }
      } else {
        for (int idx = tid; idx < B_ * 72; idx += NTHR) {
          int b = idx / 72, kk = idx - b * 72;
          int k = 384 + kk;
          float v;
          if (k < 400)      v = ald(h0prev + b * H_ + k);
          else if (k < 440) v = xr[(b * T_ + s) * 40 + (k - 400)];
          else              v = xc[(b * T_ + s) * 16 + (k - 440)];
          s_hsf[b * 128 + kk] = v;
        }
      }
      __syncthreads();
      const int nq = (ch < 3) ? 32 : 18;
      for (int i = ks; i < nq; i += 16) {
        float4 wv[U];
        #pragma unroll
        for (int j = 0; j < U; ++j)
          wv[j] = *reinterpret_cast<const float4*>(s_w + (g * U + j) * 464 + k0 + 4 * i);
        #pragma unroll
        for (int sb = 0; sb < 16; ++sb) {
          float4 hv = *reinterpret_cast<const float4*>(s_hsf + (bo * 16 + sb) * 128 + 4 * i);
          #pragma unroll
          for (int j = 0; j < U; ++j) {
            acc[sb][j] = fmaf(hv.x, wv[j].x, acc[sb][j]);
            acc[sb][j] = fmaf(hv.y, wv[j].y, acc[sb][j]);
            acc[sb][j] = fmaf(hv.z, wv[j].z, acc[sb][j]);
            acc[sb][j] = fmaf(hv.w, wv[j].w, acc[sb][j]);
          }
        }
      }
      __syncthreads();
    }
    // reduce over the 16 k-split lanes
    #pragma unroll
    for (int sb = 0; sb < 16; ++sb)
      #pragma unroll
      for (int j = 0; j < U; ++j) {
        float v = acc[sb][j];
        v += __shfl_xor(v, 1);
        v += __shfl_xor(v, 2);
        v += __shfl_xor(v, 4);
        v += __shfl_xor(v, 8);
        acc[sb][j] = v;
      }
    #pragma unroll
    for (int sb = 0; sb < 16; ++sb) {
      if (ks == sb) {
        #pragma unroll
        for (int j = 0; j < U; ++j)
          s_gs[(bo * 16 + sb) * 20 + g * U + j] = acc[sb][j];
      }
    }
    __syncthreads();
    // LSTM cell update for this block's hidden units
    for (int idx = tid; idx < B_ * U; idx += NTHR) {
      int b = idx / U; int ul = idx - b * U;
      int u = u0 + ul;
      float gi = s_gs[b * 20 + 0 * U + ul] + b0[0 * H_ + u];
      float gf = s_gs[b * 20 + 1 * U + ul] + b0[1 * H_ + u];
      float gg = s_gs[b * 20 + 2 * U + ul] + b0[2 * H_ + u];
      float go = s_gs[b * 20 + 3 * U + ul] + b0[3 * H_ + u];
      float iv = sigmf(gi), fv = sigmf(gf), gv = tanhf(gg), ov = sigmf(go);
      float cn = fv * s_cst[idx] + iv * gv;
      s_cst[idx] = cn;
      ast(h0new + b * H_ + u, ov * tanhf(cn));
    }
    publish(flags0 + s);
  }
}

// ---------------- Layer 1: gates(s) = [h0(s) ; h1(s-1)] @ [Wx1 ; Wh1], K = 800 ----------------
template<int U>
__device__ void run_l1(int u0,
    const float* __restrict__ Wx1, const float* __restrict__ Wh1, const float* __restrict__ b1,
    const float* __restrict__ h0buf, float* __restrict__ h1buf,
    int* flags0, int* flags1, int* flagsD, unsigned char* smem)
{
  const int tid = threadIdx.x;
  float*  s_hsf = (float*)smem;
  float*  s_w   = (float*)(smem + SW_OFF);
  float*  s_gs  = (float*)(smem + SGS_OFF);
  float*  s_cst = (float*)(smem + SCST_OFF);
  const int C = 4 * U;
  constexpr int CPT = 2 * U;

  for (int idx = tid; idx < 800 * C; idx += NTHR) {
    int k = idx / C, c = idx - k * C;
    int g = c / U, ul = c - g * U;
    int gc = g * H_ + u0 + ul;
    float v = (k < 400) ? Wx1[k * G4H + gc] : Wh1[(k - 400) * G4H + gc];
    s_w[c * 816 + k] = v;
  }
  for (int idx = tid; idx < B_ * U; idx += NTHR) s_cst[idx] = 0.f;
  __syncthreads();

  const int ks = tid & 31;          // k-split 32
  const int cg = (tid >> 5) & 1;    // column group
  const int bo = tid >> 6;          // batch group

  for (int s = 0; s < T_; ++s) {
    const float* h0cur  = h0buf + (s & 3) * SL;          // h0(s)
    const float* h1prev = h1buf + ((s - 1) & 3) * SL;    // h1(s-1)
    float*       h1new  = h1buf + (s & 3) * SL;

    if (tid == 0)             waitflag(flags0 + s, G0N);       // h0(s) ready
    if (tid == 64  && s >= 1) waitflag(flags1 + s - 1, G1N);   // full h1(s-1) ready
    if (tid == 128 && s >= 4) waitflag(flagsD + s - 4, 1);     // slot s&3 free (dense read h1(s-4))
    __syncthreads();

    float acc[16][CPT];
    #pragma unroll
    for (int i = 0; i < 16; ++i)
      #pragma unroll
      for (int j = 0; j < CPT; ++j) acc[i][j] = 0.f;

    for (int ch = 0; ch < 7; ++ch) {
      const int k0 = ch * 128;
      if (ch < 6) {
        for (int idx = tid; idx < B_ * 128; idx += NTHR) {
          int b = idx >> 7, kk = idx & 127;
          int k = k0 + kk;
          float v = (k < 400) ? ald(h0cur + b * H_ + k)
                              : ald(h1prev + b * H_ + (k - 400));
          s_hsf[idx] = v;
        }
      } else {
        for (int idx = tid; idx < B_ * 32; idx += NTHR) {
          int b = idx >> 5, kk = idx & 31;
          s_hsf[b * 128 + kk] = ald(h1prev + b * H_ + 368 + kk);
        }
      }
      __syncthreads();
      const int nq = (ch < 6) ? 32 : 8;
      for (int i = ks; i < nq; i += 32) {
        float4 wv[CPT];
        #pragma unroll
        for (int j = 0; j < CPT; ++j)
          wv[j] = *reinterpret_cast<const float4*>(s_w + (cg * CPT + j) * 816 + k0 + 4 * i);
        #pragma unroll
        for (int sb = 0; sb < 16; ++sb) {
          float4 hv = *reinterpret_cast<const float4*>(s_hsf + (bo * 16 + sb) * 128 + 4 * i);
          #pragma unroll
          for (int j = 0; j < CPT; ++j) {
            acc[sb][j] = fmaf(hv.x, wv[j].x, acc[sb][j]);
            acc[sb][j] = fmaf(hv.y, wv[j].y, acc[sb][j]);
            acc[sb][j] = fmaf(hv.z, wv[j].z, acc[sb][j]);
            acc[sb][j] = fmaf(hv.w, wv[j].w, acc[sb][j]);
          }
        }
      }
      __syncthreads();
    }
    #pragma unroll
    for (int sb = 0; sb < 16; ++sb)
      #pragma unroll
      for (int j = 0; j < CPT; ++j) {
        float v = acc[sb][j];
        v += __shfl_xor(v, 1);
        v += __shfl_xor(v, 2);
        v += __shfl_xor(v, 4);
        v += __shfl_xor(v, 8);
        v += __shfl_xor(v, 16);
        acc[sb][j] = v;
      }
    #pragma unroll
    for (int sb = 0; sb < 16; ++sb) {
      if (ks == sb) {
        #pragma unroll
        for (int j = 0; j < CPT; ++j)
          s_gs[(bo * 16 + sb) * 20 + cg * CPT + j] = acc[sb][j];
      }
    }
    __syncthreads();
    for (int idx = tid; idx < B_ * U; idx += NTHR) {
      int b = idx / U; int ul = idx - b * U;
      int u = u0 + ul;
      float gi = s_gs[b * 20 + 0 * U + ul] + b1[0 * H_ + u];
      float gf = s_gs[b * 20 + 1 * U + ul] + b1[1 * H_ + u];
      float gg = s_gs[b * 20 + 2 * U + ul] + b1[2 * H_ + u];
      float go = s_gs[b * 20 + 3 * U + ul] + b1[3 * H_ + u];
      float iv = sigmf(gi), fv = sigmf(gf), gv = tanhf(gg), ov = sigmf(go);
      float cn = fv * s_cst[idx] + iv * gv;
      s_cst[idx] = cn;
      ast(h1new + b * H_ + u, ov * tanhf(cn));
    }
    publish(flags1 + s);
  }
}

// ---------------- Dense head: out(s) = h1(s) @ Wd + bd ----------------
__device__ void run_dense(const float* __restrict__ Wd, const float* __restrict__ bd,
                          const float* __restrict__ h1buf, float* __restrict__ out,
                          int* flags1, int* flagsD, unsigned char* smem)
{
  const int tid = threadIdx.x;
  float* s_wd = (float*)(smem + SW_OFF);
  for (int idx = tid; idx < 1600; idx += NTHR) s_wd[idx] = Wd[idx];
  __syncthreads();
  const int b = tid >> 2, f = tid & 3;
  const float bdv = bd[f];
  for (int s = 0; s < T_; ++s) {
    if (tid == 0) waitflag(flags1 + s, G1N);
    __syncthreads();
    const float* h1t = h1buf + (s & 3) * SL;
    float acc = 0.f;
    for (int k = 0; k < 400; k += 4) {
      acc = fmaf(ald(h1t + b * H_ + k + 0), s_wd[(k + 0) * 4 + f], acc);
      acc = fmaf(ald(h1t + b * H_ + k + 1), s_wd[(k + 1) * 4 + f], acc);
      acc = fmaf(ald(h1t + b * H_ + k + 2), s_wd[(k + 2) * 4 + f], acc);
      acc = fmaf(ald(h1t + b * H_ + k + 3), s_wd[(k + 3) * 4 + f], acc);
    }
    out[(b * T_ + s) * 4 + f] = acc + bdv;
    publish(flagsD + s);   // also guarantees our reads of h1(s) are complete
  }
}

__global__ __launch_bounds__(NTHR, 2) void rnn_kernel(
    const float* __restrict__ xr, const float* __restrict__ xc,
    const float* __restrict__ Wx0, const float* __restrict__ Wh0, const float* __restrict__ b0,
    const float* __restrict__ Wx1, const float* __restrict__ Wh1, const float* __restrict__ b1,
    const float* __restrict__ Wd, const float* __restrict__ bd,
    float* __restrict__ out, float* ws)
{
  __shared__ __align__(16) unsigned char smem[SMEM_BYTES];
  const int bid = blockIdx.x;
  int* flags0 = (int*)ws;              // [1024]
  int* flags1 = flags0 + 1024;         // [1024]
  int* flagsD = flags1 + 1024;         // [1024]
  float* h0buf = (float*)(flagsD + 1024);   // [4][128][400]
  float* h1buf = h0buf + 4 * SL;            // [4][128][400]
  if (bid < G0N) {
    int u0 = bid * H_ / G0N, u1 = (bid + 1) * H_ / G0N;
    if (u1 - u0 == 5) run_l0<5>(u0, xr, xc, Wx0, Wh0, b0, h0buf, flags0, flags1, smem);
    else              run_l0<4>(u0, xr, xc, Wx0, Wh0, b0, h0buf, flags0, flags1, smem);
  } else if (bid < G0N + G1N) {
    int j = bid - G0N;
    int u0 = j * H_ / G1N, u1 = (j + 1) * H_ / G1N;
    if (u1 - u0 == 3) run_l1<3>(u0, Wx1, Wh1, b1, h0buf, h1buf, flags0, flags1, flagsD, smem);
    else              run_l1<2>(u0, Wx1, Wh1, b1, h0buf, h1buf, flags0, flags1, flagsD, smem);
  } else {
    run_dense(Wd, bd, h1buf, out, flags1, flagsD, smem);
  }
}

extern "C" void kernel_launch(void* const* d_in, const int* in_sizes, int n_in,
                              void* d_out, int out_size, void* d_ws, size_t ws_size,
                              hipStream_t stream) {
  const float* xr  = (const float*)d_in[0];
  const float* xc  = (const float*)d_in[1];
  const float* Wx0 = (const float*)d_in[2];
  const float* Wh0 = (const float*)d_in[3];
  const float* b0  = (const float*)d_in[4];
  const float* Wx1 = (const float*)d_in[5];
  const float* Wh1 = (const float*)d_in[6];
  const float* b1  = (const float*)d_in[7];
  const float* Wd  = (const float*)d_in[8];
  const float* bd  = (const float*)d_in[9];
  float* out = (float*)d_out;
  float* ws  = (float*)d_ws;

  // zero: flag arrays (3*1024 ints) + slot 3 of h0buf and h1buf (the s=-1 state)
  hipMemsetAsync(d_ws, 0, 3 * 1024 * sizeof(int), stream);
  hipMemsetAsync((char*)d_ws + 12288 + 3 * SL * 4, 0, SL * 4, stream);
  hipMemsetAsync((char*)d_ws + 12288 + 4 * SL * 4 + 3 * SL * 4, 0, SL * 4, stream);
  hipLaunchKernelGGL(rnn_kernel, dim3(NBLK), dim3(NTHR), 0, stream,
                     xr, xc, Wx0, Wh0, b0, Wx1, Wh1, b1, Wd, bd, out, ws);
}

// Round 3
// 33214.050 us; speedup vs baseline: 2.4548x; 1.8543x over previous
//
#include <hip/hip_runtime.h>

#define B_ 128
#define T_ 1024
#define H_ 400
#define G4H 1600
#define NBLK 256
#define NTHR 512
#define G0N 86
#define G1N 169
#define SL (B_ * H_)   // floats per h slot

typedef float f32x4 __attribute__((ext_vector_type(4)));

// shared memory layout (bytes)
#define SHS_BYTES (B_ * 32 * 16)               // 65536: staging buffer (L1: 128-wide, L0: 80-wide)
#define SW_OFF    SHS_BYTES
#define SW_FLOATS 9792                          // max(20*488=9760, 12*816=9792)
#define SGS_OFF   (SW_OFF + SW_FLOATS * 4)      // gate staging 128 x 20 floats
#define SCST_OFF  (SGS_OFF + 2560 * 4)          // cell state 128 x 5 floats
#define SMEM_BYTES (SCST_OFF + 640 * 4)         // 117504 total

#define SCOPE __HIP_MEMORY_SCOPE_AGENT

__device__ __forceinline__ float sigmf(float x) { return 1.0f / (1.0f + __expf(-x)); }

// coherent 16B load: bypasses (non-coherent) L1/L2, served by LLC. Value is NOT
// valid until a subsequent vwait0() — batch issues, then wait once.
__device__ __forceinline__ void cload4(f32x4& r, const float* p) {
  asm volatile("global_load_dwordx4 %0, %1, off sc0 sc1" : "=v"(r) : "v"(p) : "memory");
}
__device__ __forceinline__ void vwait0() {
  asm volatile("s_waitcnt vmcnt(0)" ::: "memory");
  __builtin_amdgcn_sched_barrier(0);   // rule #18: keep consumers below the wait
}
__device__ __forceinline__ void ast(float* p, float v) {
  __hip_atomic_store(p, v, __ATOMIC_RELAXED, SCOPE);      // write-through to LLC
}
__device__ __forceinline__ void waitflag(int* f, int tgt) {
  while (__hip_atomic_load(f, __ATOMIC_RELAXED, SCOPE) < tgt)
    __builtin_amdgcn_s_sleep(1);
}
// all waves drain their global ops, then one lane bumps the counter
__device__ __forceinline__ void publish(int* f) {
  asm volatile("s_waitcnt vmcnt(0)" ::: "memory");
  __syncthreads();
  if (threadIdx.x == 0) __hip_atomic_fetch_add(f, 1, __ATOMIC_RELAXED, SCOPE);
}

// ---------------- Layer 0: gates(s) = [h0(s-1) ; x(s)] @ [Wh0 ; Wx0], K = 456 (pad 480) ----------------
// K layout: [0,400) h0prev | [400,440) xr | [440,456) xc | [456,480) zero-pad
// 6 chunks of width 80; per thread per chunk: 5 x4 coherent loads.
template<int U>
__device__ void run_l0(int u0,
    const float* __restrict__ xr, const float* __restrict__ xc,
    const float* __restrict__ Wx0, const float* __restrict__ Wh0, const float* __restrict__ b0,
    float* __restrict__ h0buf, int* flags0, int* flags1, unsigned char* smem)
{
  const int tid = threadIdx.x;
  float*  s_hsf = (float*)smem;                 // [128][80]
  float*  s_w   = (float*)(smem + SW_OFF);      // [C][488]
  float*  s_gs  = (float*)(smem + SGS_OFF);
  float*  s_cst = (float*)(smem + SCST_OFF);
  const int C = 4 * U;

  // stage weight slice once, K padded to 480 with zeros
  for (int idx = tid; idx < 480 * C; idx += NTHR) {
    int k = idx / C, c = idx - k * C;
    int g = c / U, ul = c - g * U;
    int gc = g * H_ + u0 + ul;
    float v = 0.f;
    if (k < 400)      v = Wh0[k * G4H + gc];
    else if (k < 456) v = Wx0[(k - 400) * G4H + gc];
    s_w[c * 488 + k] = v;
  }
  for (int idx = tid; idx < B_ * U; idx += NTHR) s_cst[idx] = 0.f;
  __syncthreads();

  const int ks = tid & 15;          // k-split 16
  const int g  = (tid >> 4) & 3;    // gate group
  const int bo = tid >> 6;          // batch group (0..7) = wave id

  f32x4 r[5];
  for (int s = 0; s < T_; ++s) {
    const float* h0prev = h0buf + ((s - 1) & 3) * SL;
    float*       h0new  = h0buf + (s & 3) * SL;

    if (tid == 0  && s >= 1) waitflag(flags0 + s - 1, G0N);  // full h0(s-1) ready
    if (tid == 64 && s >= 4) waitflag(flags1 + s - 4, G1N);  // slot s&3 free
    __syncthreads();

    float acc[16][U];
    #pragma unroll
    for (int i = 0; i < 16; ++i)
      #pragma unroll
      for (int j = 0; j < U; ++j) acc[i][j] = 0.f;

    auto issue = [&](int c) {
      #pragma unroll
      for (int kk = 0; kk < 5; ++kk) {
        int sidx = tid + NTHR * kk;            // 0..2559
        int b = sidx / 20, q = sidx - 20 * b;  // 20 x4-slots per row
        int kidx = 80 * c + 4 * q;
        const float* p = (kidx < 400) ? (h0prev + b * H_ + kidx)
                       : (kidx < 440) ? (xr + (b * T_ + s) * 40 + (kidx - 400))
                       : (kidx < 456) ? (xc + (b * T_ + s) * 16 + (kidx - 440))
                                      : xc;    // pad: weights are zero
        cload4(r[kk], p);
      }
    };

    issue(0);
    for (int c = 0; c < 6; ++c) {
      if (c > 0) __syncthreads();   // prev chunk's compute done on all threads
      vwait0();                      // chunk c's loads landed
      #pragma unroll
      for (int kk = 0; kk < 5; ++kk) {
        int sidx = tid + NTHR * kk;
        int b = sidx / 20, q = sidx - 20 * b;
        ((f32x4*)s_hsf)[b * 20 + q] = r[kk];
      }
      if (c + 1 < 6) issue(c + 1);  // prefetch next chunk (latency hides under sync+compute)
      __syncthreads();
      const int k0 = 80 * c;
      for (int i = ks; i < 20; i += 16) {
        f32x4 wv[U];
        #pragma unroll
        for (int j = 0; j < U; ++j)
          wv[j] = *(const f32x4*)(s_w + (g * U + j) * 488 + k0 + 4 * i);
        #pragma unroll
        for (int sb = 0; sb < 16; ++sb) {
          f32x4 hv = *(const f32x4*)(s_hsf + (bo * 16 + sb) * 80 + 4 * i);
          #pragma unroll
          for (int j = 0; j < U; ++j) {
            acc[sb][j] = fmaf(hv.x, wv[j].x, acc[sb][j]);
            acc[sb][j] = fmaf(hv.y, wv[j].y, acc[sb][j]);
            acc[sb][j] = fmaf(hv.z, wv[j].z, acc[sb][j]);
            acc[sb][j] = fmaf(hv.w, wv[j].w, acc[sb][j]);
          }
        }
      }
    }
    // reduce over the 16 k-split lanes
    #pragma unroll
    for (int sb = 0; sb < 16; ++sb)
      #pragma unroll
      for (int j = 0; j < U; ++j) {
        float v = acc[sb][j];
        v += __shfl_xor(v, 1);
        v += __shfl_xor(v, 2);
        v += __shfl_xor(v, 4);
        v += __shfl_xor(v, 8);
        acc[sb][j] = v;
      }
    #pragma unroll
    for (int sb = 0; sb < 16; ++sb) {
      if (ks == sb) {
        #pragma unroll
        for (int j = 0; j < U; ++j)
          s_gs[(bo * 16 + sb) * 20 + g * U + j] = acc[sb][j];
      }
    }
    __syncthreads();
    // LSTM cell update for this block's hidden units
    for (int idx = tid; idx < B_ * U; idx += NTHR) {
      int b = idx / U; int ul = idx - b * U;
      int u = u0 + ul;
      float gi = s_gs[b * 20 + 0 * U + ul] + b0[0 * H_ + u];
      float gf = s_gs[b * 20 + 1 * U + ul] + b0[1 * H_ + u];
      float gg = s_gs[b * 20 + 2 * U + ul] + b0[2 * H_ + u];
      float go = s_gs[b * 20 + 3 * U + ul] + b0[3 * H_ + u];
      float iv = sigmf(gi), fv = sigmf(gf), gv = tanhf(gg), ov = sigmf(go);
      float cn = fv * s_cst[idx] + iv * gv;
      s_cst[idx] = cn;
      ast(h0new + b * H_ + u, ov * tanhf(cn));
    }
    publish(flags0 + s);
  }
}

// ---------------- Layer 1: gates(s) = [h0(s) ; h1(s-1)] @ [Wx1 ; Wh1], K = 800 ----------------
// K layout: [0,400) h0cur | [400,800) h1prev. 6 chunks of 128 + 1 chunk of 32.
template<int U>
__device__ void run_l1(int u0,
    const float* __restrict__ Wx1, const float* __restrict__ Wh1, const float* __restrict__ b1,
    const float* __restrict__ h0buf, float* __restrict__ h1buf,
    int* flags0, int* flags1, int* flagsD, unsigned char* smem)
{
  const int tid = threadIdx.x;
  float*  s_hsf = (float*)smem;                 // [128][128]
  float*  s_w   = (float*)(smem + SW_OFF);      // [C][816]
  float*  s_gs  = (float*)(smem + SGS_OFF);
  float*  s_cst = (float*)(smem + SCST_OFF);
  const int C = 4 * U;
  constexpr int CPT = 2 * U;

  for (int idx = tid; idx < 800 * C; idx += NTHR) {
    int k = idx / C, c = idx - k * C;
    int g = c / U, ul = c - g * U;
    int gc = g * H_ + u0 + ul;
    float v = (k < 400) ? Wx1[k * G4H + gc] : Wh1[(k - 400) * G4H + gc];
    s_w[c * 816 + k] = v;
  }
  for (int idx = tid; idx < B_ * U; idx += NTHR) s_cst[idx] = 0.f;
  __syncthreads();

  const int ks = tid & 31;          // k-split 32
  const int cg = (tid >> 5) & 1;    // column group
  const int bo = tid >> 6;          // batch group

  f32x4 r[8];
  for (int s = 0; s < T_; ++s) {
    const float* h0cur  = h0buf + (s & 3) * SL;          // h0(s)
    const float* h1prev = h1buf + ((s - 1) & 3) * SL;    // h1(s-1)
    float*       h1new  = h1buf + (s & 3) * SL;

    if (tid == 0)             waitflag(flags0 + s, G0N);       // h0(s) ready
    if (tid == 64  && s >= 1) waitflag(flags1 + s - 1, G1N);   // full h1(s-1) ready
    if (tid == 128 && s >= 4) waitflag(flagsD + s - 4, 1);     // slot s&3 free
    __syncthreads();

    float acc[16][CPT];
    #pragma unroll
    for (int i = 0; i < 16; ++i)
      #pragma unroll
      for (int j = 0; j < CPT; ++j) acc[i][j] = 0.f;

    auto issue = [&](int c) {
      if (c < 6) {
        #pragma unroll
        for (int kk = 0; kk < 8; ++kk) {
          int b = (tid >> 5) + 16 * kk;
          int kidx = 128 * c + 4 * (tid & 31);
          const float* p = (kidx < 400) ? (h0cur + b * H_ + kidx)
                                        : (h1prev + b * H_ + (kidx - 400));
          cload4(r[kk], p);
        }
      } else {
        #pragma unroll
        for (int kk = 0; kk < 2; ++kk) {
          int b = (tid >> 3) + 64 * kk;
          int kidx = 768 + 4 * (tid & 7);            // 768..796, all h1
          cload4(r[kk], h1prev + b * H_ + (kidx - 400));
        }
      }
    };

    issue(0);
    for (int c = 0; c < 7; ++c) {
      if (c > 0) __syncthreads();
      vwait0();
      if (c < 6) {
        #pragma unroll
        for (int kk = 0; kk < 8; ++kk) {
          int b = (tid >> 5) + 16 * kk;
          ((f32x4*)s_hsf)[b * 32 + (tid & 31)] = r[kk];
        }
      } else {
        #pragma unroll
        for (int kk = 0; kk < 2; ++kk) {
          int b = (tid >> 3) + 64 * kk;
          ((f32x4*)s_hsf)[b * 32 + (tid & 7)] = r[kk];
        }
      }
      if (c + 1 < 7) issue(c + 1);
      __syncthreads();
      const int k0 = 128 * c;
      const int nq = (c < 6) ? 32 : 8;
      for (int i = ks; i < nq; i += 32) {
        f32x4 wv[CPT];
        #pragma unroll
        for (int j = 0; j < CPT; ++j)
          wv[j] = *(const f32x4*)(s_w + (cg * CPT + j) * 816 + k0 + 4 * i);
        #pragma unroll
        for (int sb = 0; sb < 16; ++sb) {
          f32x4 hv = *(const f32x4*)(s_hsf + (bo * 16 + sb) * 128 + 4 * i);
          #pragma unroll
          for (int j = 0; j < CPT; ++j) {
            acc[sb][j] = fmaf(hv.x, wv[j].x, acc[sb][j]);
            acc[sb][j] = fmaf(hv.y, wv[j].y, acc[sb][j]);
            acc[sb][j] = fmaf(hv.z, wv[j].z, acc[sb][j]);
            acc[sb][j] = fmaf(hv.w, wv[j].w, acc[sb][j]);
          }
        }
      }
    }
    #pragma unroll
    for (int sb = 0; sb < 16; ++sb)
      #pragma unroll
      for (int j = 0; j < CPT; ++j) {
        float v = acc[sb][j];
        v += __shfl_xor(v, 1);
        v += __shfl_xor(v, 2);
        v += __shfl_xor(v, 4);
        v += __shfl_xor(v, 8);
        v += __shfl_xor(v, 16);
        acc[sb][j] = v;
      }
    #pragma unroll
    for (int sb = 0; sb < 16; ++sb) {
      if (ks == sb) {
        #pragma unroll
        for (int j = 0; j < CPT; ++j)
          s_gs[(bo * 16 + sb) * 20 + cg * CPT + j] = acc[sb][j];
      }
    }
    __syncthreads();
    for (int idx = tid; idx < B_ * U; idx += NTHR) {
      int b = idx / U; int ul = idx - b * U;
      int u = u0 + ul;
      float gi = s_gs[b * 20 + 0 * U + ul] + b1[0 * H_ + u];
      float gf = s_gs[b * 20 + 1 * U + ul] + b1[1 * H_ + u];
      float gg = s_gs[b * 20 + 2 * U + ul] + b1[2 * H_ + u];
      float go = s_gs[b * 20 + 3 * U + ul] + b1[3 * H_ + u];
      float iv = sigmf(gi), fv = sigmf(gf), gv = tanhf(gg), ov = sigmf(go);
      float cn = fv * s_cst[idx] + iv * gv;
      s_cst[idx] = cn;
      ast(h1new + b * H_ + u, ov * tanhf(cn));
    }
    publish(flags1 + s);
  }
}

// ---------------- Dense head: out(s) = h1(s) @ Wd + bd ----------------
// 512 threads = 128 b x 4-way k-split; 25 x4 coherent loads per thread, one wait.
__device__ void run_dense(const float* __restrict__ Wd, const float* __restrict__ bd,
                          const float* __restrict__ h1buf, float* __restrict__ out,
                          int* flags1, int* flagsD, unsigned char* smem)
{
  const int tid = threadIdx.x;
  float* s_wd = (float*)(smem + SW_OFF);        // [400][4]
  for (int idx = tid; idx < 1600; idx += NTHR) s_wd[idx] = Wd[idx];
  __syncthreads();
  const int b = tid >> 2, ks = tid & 3;
  const int k0 = ks * 100;
  const float bdv = bd[ks];
  f32x4 r[25];
  for (int s = 0; s < T_; ++s) {
    if (tid == 0) waitflag(flags1 + s, G1N);
    __syncthreads();
    const float* h1t = h1buf + (s & 3) * SL + b * H_ + k0;
    #pragma unroll
    for (int j = 0; j < 25; ++j) cload4(r[j], h1t + 4 * j);
    vwait0();
    f32x4 acc = {0.f, 0.f, 0.f, 0.f};
    #pragma unroll
    for (int j = 0; j < 25; ++j) {
      #pragma unroll
      for (int kk = 0; kk < 4; ++kk) {
        f32x4 w = ((const f32x4*)s_wd)[k0 + 4 * j + kk];
        float h = r[j][kk];
        acc.x = fmaf(h, w.x, acc.x);
        acc.y = fmaf(h, w.y, acc.y);
        acc.z = fmaf(h, w.z, acc.z);
        acc.w = fmaf(h, w.w, acc.w);
      }
    }
    float a0 = acc.x, a1 = acc.y, a2 = acc.z, a3 = acc.w;
    a0 += __shfl_xor(a0, 1); a0 += __shfl_xor(a0, 2);
    a1 += __shfl_xor(a1, 1); a1 += __shfl_xor(a1, 2);
    a2 += __shfl_xor(a2, 1); a2 += __shfl_xor(a2, 2);
    a3 += __shfl_xor(a3, 1); a3 += __shfl_xor(a3, 2);
    float v = (ks == 0) ? a0 : (ks == 1) ? a1 : (ks == 2) ? a2 : a3;
    out[(b * T_ + s) * 4 + ks] = v + bdv;
    publish(flagsD + s);   // also guarantees our reads of h1(s) are drained
  }
}

__global__ __launch_bounds__(NTHR, 2) void rnn_kernel(
    const float* __restrict__ xr, const float* __restrict__ xc,
    const float* __restrict__ Wx0, const float* __restrict__ Wh0, const float* __restrict__ b0,
    const float* __restrict__ Wx1, const float* __restrict__ Wh1, const float* __restrict__ b1,
    const float* __restrict__ Wd, const float* __restrict__ bd,
    float* __restrict__ out, float* ws)
{
  __shared__ __align__(16) unsigned char smem[SMEM_BYTES];
  const int bid = blockIdx.x;
  int* flags0 = (int*)ws;              // [1024]
  int* flags1 = flags0 + 1024;         // [1024]
  int* flagsD = flags1 + 1024;         // [1024]
  float* h0buf = (float*)(flagsD + 1024);   // [4][128][400]
  float* h1buf = h0buf + 4 * SL;            // [4][128][400]
  if (bid < G0N) {
    int u0 = bid * H_ / G0N, u1 = (bid + 1) * H_ / G0N;
    if (u1 - u0 == 5) run_l0<5>(u0, xr, xc, Wx0, Wh0, b0, h0buf, flags0, flags1, smem);
    else              run_l0<4>(u0, xr, xc, Wx0, Wh0, b0, h0buf, flags0, flags1, smem);
  } else if (bid < G0N + G1N) {
    int j = bid - G0N;
    int u0 = j * H_ / G1N, u1 = (j + 1) * H_ / G1N;
    if (u1 - u0 == 3) run_l1<3>(u0, Wx1, Wh1, b1, h0buf, h1buf, flags0, flags1, flagsD, smem);
    else              run_l1<2>(u0, Wx1, Wh1, b1, h0buf, h1buf, flags0, flags1, flagsD, smem);
  } else {
    run_dense(Wd, bd, h1buf, out, flags1, flagsD, smem);
  }
}

extern "C" void kernel_launch(void* const* d_in, const int* in_sizes, int n_in,
                              void* d_out, int out_size, void* d_ws, size_t ws_size,
                              hipStream_t stream) {
  const float* xr  = (const float*)d_in[0];
  const float* xc  = (const float*)d_in[1];
  const float* Wx0 = (const float*)d_in[2];
  const float* Wh0 = (const float*)d_in[3];
  const float* b0  = (const float*)d_in[4];
  const float* Wx1 = (const float*)d_in[5];
  const float* Wh1 = (const float*)d_in[6];
  const float* b1  = (const float*)d_in[7];
  const float* Wd  = (const float*)d_in[8];
  const float* bd  = (const float*)d_in[9];
  float* out = (float*)d_out;
  float* ws  = (float*)d_ws;

  // zero: flag arrays (3*1024 ints) + slot 3 of h0buf and h1buf (the s=-1 state)
  hipMemsetAsync(d_ws, 0, 3 * 1024 * sizeof(int), stream);
  hipMemsetAsync((char*)d_ws + 12288 + 3 * SL * 4, 0, SL * 4, stream);
  hipMemsetAsync((char*)d_ws + 12288 + 4 * SL * 4 + 3 * SL * 4, 0, SL * 4, stream);
  hipLaunchKernelGGL(rnn_kernel, dim3(NBLK), dim3(NTHR), 0, stream,
                     xr, xc, Wx0, Wh0, b0, Wx1, Wh1, b1, Wd, bd, out, ws);
}

// Round 5
// 19493.111 us; speedup vs baseline: 4.1826x; 1.7039x over previous
//
#include <hip/hip_runtime.h>

#define B_ 128
#define T_ 1024
#define H_ 400
#define G4H 1600
#define NBLK 256
#define NTHR 512
#define G0N 86
#define G1N 169
#define SL (B_ * H_)   // halfs per h slot
#define SCOPE __HIP_MEMORY_SCOPE_AGENT

typedef float f32x4 __attribute__((ext_vector_type(4)));
typedef _Float16 h2 __attribute__((ext_vector_type(2)));
typedef _Float16 h4 __attribute__((ext_vector_type(4)));
union V4 { f32x4 f; h2 h[4]; };

// LDS layout (bytes): one 128x256-half staging buf + fp16 weights + fp32 gates/cell
#define SWOFF 65536
#define SGS   85312
#define SCST  95552
#define SMEMB 98112

__device__ __forceinline__ float sigmf(float x) { return 1.0f / (1.0f + __expf(-x)); }

// coherent 16B load (LLC-served, bypasses non-coherent L1/L2). Valid only after vwait0().
__device__ __forceinline__ void cload4(f32x4& r, const void* p) {
  asm volatile("global_load_dwordx4 %0, %1, off sc0 sc1" : "=v"(r) : "v"(p) : "memory");
}
// plain cached 16B load (immutable inputs only)
__device__ __forceinline__ void pload4(f32x4& r, const void* p) {
  asm volatile("global_load_dwordx4 %0, %1, off" : "=v"(r) : "v"(p) : "memory");
}
// drain ALL outstanding vmem (count-independent -> immune to compiler-inserted vmem/spills)
__device__ __forceinline__ void vwait0() {
  asm volatile("s_waitcnt vmcnt(0)" ::: "memory");
  __builtin_amdgcn_sched_barrier(0);   // rule #18
}

__device__ __forceinline__ float dot2f(h2 a, h2 b, float c) {
#if __has_builtin(__builtin_amdgcn_fdot2)
  return __builtin_amdgcn_fdot2(a, b, c, false);
#else
  return fmaf((float)a[0], (float)b[0], fmaf((float)a[1], (float)b[1], c));
#endif
}

// wave-parallel poll of 8 per-group sub-counters (lane&7 -> group); whole wave calls.
__device__ __forceinline__ void poll8(const int* p, int tgt) {
  for (;;) {
    int v;
    asm volatile("global_load_dword %0, %1, off sc0 sc1\n\ts_waitcnt vmcnt(0)"
                 : "=v"(v) : "v"(p) : "memory");
    if (__all(v >= tgt)) return;
    __builtin_amdgcn_s_sleep(1);
  }
}
__device__ __forceinline__ void publish(int* f) {
  asm volatile("s_waitcnt vmcnt(0)" ::: "memory");   // drain this thread's h-stores
  __syncthreads();                                    // all threads drained
  if (threadIdx.x == 0) __hip_atomic_fetch_add(f, 1, __ATOMIC_RELAXED, SCOPE);
}
__device__ __forceinline__ void cstoreh(_Float16* p, float v) {
  union { _Float16 h; unsigned short s; } cv; cv.h = (_Float16)v;
  unsigned u = cv.s;
  asm volatile("global_store_short %0, %1, off sc0 sc1" :: "v"(p), "v"(u) : "memory");
}
__device__ __forceinline__ void cstorei(int* p, int v) {
  asm volatile("global_store_dword %0, %1, off sc0 sc1" :: "v"(p), "v"(v) : "memory");
}

// one K-chunk of the per-block GEMM: acc[sb][j] += h[sb][.] . w[g*U+j][.], staging stride 256 halfs
template<int U>
__device__ __forceinline__ void cchunk(float (&acc)[16][U], const _Float16* s_w, int wstride,
                                       const _Float16* s_h, int k0w, int nslot,
                                       int ks, int g, int bo)
{
  for (int i = ks; i < nslot; i += 16) {
    V4 wv4[U];
    #pragma unroll
    for (int j = 0; j < U; ++j)
      wv4[j].f = *(const f32x4*)(s_w + (g * U + j) * wstride + k0w + i * 8);
    #pragma unroll
    for (int sb = 0; sb < 16; ++sb) {
      V4 hv;
      hv.f = *(const f32x4*)(s_h + (bo * 16 + sb) * 256 + i * 8);
      #pragma unroll
      for (int j = 0; j < U; ++j)
        #pragma unroll
        for (int q = 0; q < 4; ++q)
          acc[sb][j] = dot2f(hv.h[q], wv4[j].h[q], acc[sb][j]);
    }
  }
}

// ---------------- Layer 0: gates(s) = [h0(s-1); x(s)] @ [Wh0; Wx0], packed K = 464 ----------------
// chunk0: K[0,256) h. chunk1: K[256,464) = h[256,400) + x56 + pad8, staged at cols 0..208.
template<int U>
__device__ void run_l0(int li, int u0,
    const float* __restrict__ xr, const float* __restrict__ xc,
    const float* __restrict__ Wx0, const float* __restrict__ Wh0, const float* __restrict__ b0,
    _Float16* __restrict__ h0buf, int* f0g, int* f1g, unsigned char* smem)
{
  const int tid = threadIdx.x;
  _Float16* s_h = (_Float16*)smem;              // [128][256]
  _Float16* s_w = (_Float16*)(smem + SWOFF);    // [C][472]
  float* s_gs  = (float*)(smem + SGS);
  float* s_cst = (float*)(smem + SCST);
  const int C = 4 * U, WS = 472;

  for (int idx = tid; idx < 464 * C; idx += NTHR) {
    int k = idx / C, c = idx - k * C;
    int g = c / U, ul = c - g * U, gc = g * H_ + u0 + ul;
    float v = 0.f;
    if (k < 400) v = Wh0[k * G4H + gc];
    else if (k < 456) v = Wx0[(k - 400) * G4H + gc];
    s_w[c * WS + k] = (_Float16)v;
  }
  for (int idx = tid; idx < B_ * U; idx += NTHR) s_cst[idx] = 0.f;
  __syncthreads();

  const int ks = tid & 15, g = (tid >> 4) & 3, bo = tid >> 6;
  const int wv = tid >> 6, myg = tid & 7;
  const int t0 = (myg < 6) ? 11 : 10;   // 86 = 6*11 + 2*10
  const int t1 = (myg < 1) ? 22 : 21;   // 169 = 1*22 + 7*21
  int* pub = f0g + (li & 7) * 1024;

  f32x4 rx[4], r[8];

  for (int s = 0; s < T_; ++s) {
    const _Float16* h0p = h0buf + ((s - 1) & 3) * SL;
    _Float16* h0n = h0buf + (s & 3) * SL;

    // pre-issue x loads (plain cached; values consumed in chunk 1)
    #pragma unroll
    for (int k = 0; k < 4; ++k) {
      int slot = tid + NTHR * k;
      if (slot < 1792) {
        int row = slot / 14, c4 = slot - row * 14, kf = c4 * 4;
        const float* p = (kf < 40) ? xr + (row * T_ + s) * 40 + kf
                                   : xc + (row * T_ + s) * 16 + (kf - 40);
        pload4(rx[k], p);
      }
    }
    if (wv == 0 && s >= 1) poll8(f0g + myg * 1024 + (s - 1), t0);  // h0(s-1) complete
    if (wv == 1 && s >= 4) poll8(f1g + myg * 1024 + (s - 4), t1);  // slot s&3 free
    __syncthreads();

    float acc[16][U];
    #pragma unroll
    for (int i = 0; i < 16; ++i)
      #pragma unroll
      for (int j = 0; j < U; ++j) acc[i][j] = 0.f;

    // ---- chunk 0: K[0,256), 8 loads/thread
    #pragma unroll
    for (int k = 0; k < 8; ++k) {
      int slot = tid + NTHR * k, row = slot >> 5, c8 = slot & 31;
      cload4(r[k], h0p + row * H_ + c8 * 8);
    }
    vwait0();                                  // drains rx + c0 (regs stay valid)
    #pragma unroll
    for (int k = 0; k < 8; ++k) {
      int slot = tid + NTHR * k, row = slot >> 5, c8 = slot & 31;
      *(f32x4*)(s_h + row * 256 + c8 * 8) = r[k];
    }
    // issue chunk-1 h-part: K[256,400) = 18 slots/row = 2304 slots
    #pragma unroll
    for (int k = 0; k < 5; ++k) {
      int slot = tid + NTHR * k;
      if (slot < 2304) {
        int row = slot / 18, c8 = slot - row * 18;
        cload4(r[k], h0p + row * H_ + 256 + c8 * 8);
      }
    }
    __syncthreads();
    cchunk<U>(acc, s_w, WS, s_h, 0, 32, ks, g, bo);
    __syncthreads();                           // all done reading chunk 0
    vwait0();                                  // chunk-1 loads landed
    #pragma unroll
    for (int k = 0; k < 5; ++k) {
      int slot = tid + NTHR * k;
      if (slot < 2304) {
        int row = slot / 18, c8 = slot - row * 18;
        *(f32x4*)(s_h + row * 256 + c8 * 8) = r[k];
      }
    }
    #pragma unroll
    for (int k = 0; k < 4; ++k) {
      int slot = tid + NTHR * k;
      if (slot < 1792) {
        int row = slot / 14, c4 = slot - row * 14;
        h4 hv; hv[0] = (_Float16)rx[k][0]; hv[1] = (_Float16)rx[k][1];
               hv[2] = (_Float16)rx[k][2]; hv[3] = (_Float16)rx[k][3];
        *(h4*)(s_h + row * 256 + 144 + c4 * 4) = hv;   // K 400+kf -> col 144+kf
      }
    }
    __syncthreads();
    cchunk<U>(acc, s_w, WS, s_h, 256, 26, ks, g, bo);  // K[256,464), pad cols x0 weights

    // reduce over 16 k-split lanes
    #pragma unroll
    for (int sb = 0; sb < 16; ++sb)
      #pragma unroll
      for (int j = 0; j < U; ++j) {
        float v = acc[sb][j];
        v += __shfl_xor(v, 1); v += __shfl_xor(v, 2);
        v += __shfl_xor(v, 4); v += __shfl_xor(v, 8);
        acc[sb][j] = v;
      }
    #pragma unroll
    for (int sb = 0; sb < 16; ++sb)
      if (ks == sb) {
        #pragma unroll
        for (int j = 0; j < U; ++j)
          s_gs[(bo * 16 + sb) * 20 + g * U + j] = acc[sb][j];
      }
    __syncthreads();
    for (int idx = tid; idx < B_ * U; idx += NTHR) {
      int b = idx / U, ul = idx - b * U, u = u0 + ul;
      float gi = s_gs[b * 20 + 0 * U + ul] + b0[0 * H_ + u];
      float gf = s_gs[b * 20 + 1 * U + ul] + b0[1 * H_ + u];
      float gg = s_gs[b * 20 + 2 * U + ul] + b0[2 * H_ + u];
      float go = s_gs[b * 20 + 3 * U + ul] + b0[3 * H_ + u];
      float iv = sigmf(gi), fv = sigmf(gf), gv = tanhf(gg), ov = sigmf(go);
      float cn = fv * s_cst[idx] + iv * gv;
      s_cst[idx] = cn;
      cstoreh(h0n + b * H_ + u, ov * tanhf(cn));
    }
    publish(pub + s);
  }
}

// ---------------- Layer 1: gates(s) = [h0(s); h1(s-1)] @ [Wx1; Wh1], K = 800 ----------------
// chunks of 256 halfs: c0 [0,256) h0; c1 [256,512) h0/h1; c2 [512,768) h1; c3 [768,800) h1 tail.
template<int U>
__device__ void run_l1(int lj, int u0,
    const float* __restrict__ Wx1, const float* __restrict__ Wh1, const float* __restrict__ b1,
    const _Float16* __restrict__ h0buf, _Float16* __restrict__ h1buf,
    int* f0g, int* f1g, int* fD, unsigned char* smem)
{
  const int tid = threadIdx.x;
  _Float16* s_h = (_Float16*)smem;              // [128][256]
  _Float16* s_w = (_Float16*)(smem + SWOFF);    // [C][824]
  float* s_gs  = (float*)(smem + SGS);
  float* s_cst = (float*)(smem + SCST);
  const int C = 4 * U, WS = 824;

  for (int idx = tid; idx < 800 * C; idx += NTHR) {
    int k = idx / C, c = idx - k * C;
    int g = c / U, ul = c - g * U, gc = g * H_ + u0 + ul;
    float v = (k < 400) ? Wx1[k * G4H + gc] : Wh1[(k - 400) * G4H + gc];
    s_w[c * WS + k] = (_Float16)v;
  }
  for (int idx = tid; idx < B_ * U; idx += NTHR) s_cst[idx] = 0.f;
  __syncthreads();

  const int ks = tid & 15, g = (tid >> 4) & 3, bo = tid >> 6;
  const int wv = tid >> 6, myg = tid & 7;
  const int t0 = (myg < 6) ? 11 : 10;
  const int t1 = (myg < 1) ? 22 : 21;
  int* pub = f1g + (lj & 7) * 1024;

  f32x4 r[8];

  for (int s = 0; s < T_; ++s) {
    const _Float16* h0c = h0buf + (s & 3) * SL;
    const _Float16* h1p = h1buf + ((s - 1) & 3) * SL;
    _Float16* h1n = h1buf + (s & 3) * SL;

    if (wv == 0)           poll8(f0g + myg * 1024 + s, t0);       // h0(s) ready
    if (wv == 1 && s >= 1) poll8(f1g + myg * 1024 + (s - 1), t1); // h1(s-1) ready
    if (wv == 2 && s >= 4) poll8(fD + (s - 4), 1);                // dense freed slot
    __syncthreads();

    float acc[16][U];
    #pragma unroll
    for (int i = 0; i < 16; ++i)
      #pragma unroll
      for (int j = 0; j < U; ++j) acc[i][j] = 0.f;

    auto issueF = [&](int c) {
      #pragma unroll
      for (int k = 0; k < 8; ++k) {
        int slot = tid + NTHR * k, row = slot >> 5, c8 = slot & 31;
        int kh = c * 256 + c8 * 8;
        const _Float16* p = (kh < 400) ? h0c + row * H_ + kh
                                       : h1p + row * H_ + (kh - 400);
        cload4(r[k], p);
      }
    };
    auto writeF = [&]() {
      #pragma unroll
      for (int k = 0; k < 8; ++k) {
        int slot = tid + NTHR * k, row = slot >> 5, c8 = slot & 31;
        *(f32x4*)(s_h + row * 256 + c8 * 8) = r[k];
      }
    };

    issueF(0);
    vwait0(); writeF(); issueF(1); __syncthreads();
    cchunk<U>(acc, s_w, WS, s_h, 0, 32, ks, g, bo);
    __syncthreads(); vwait0(); writeF(); issueF(2); __syncthreads();
    cchunk<U>(acc, s_w, WS, s_h, 256, 32, ks, g, bo);
    __syncthreads(); vwait0(); writeF();
    { int row = tid >> 2, c4 = tid & 3;                // c3 tail: K[768,800) -> h1[368,400)
      cload4(r[0], h1p + row * H_ + 368 + c4 * 8); }
    __syncthreads();
    cchunk<U>(acc, s_w, WS, s_h, 512, 32, ks, g, bo);
    __syncthreads(); vwait0();
    { int row = tid >> 2, c4 = tid & 3;
      *(f32x4*)(s_h + row * 256 + c4 * 8) = r[0]; }
    __syncthreads();
    cchunk<U>(acc, s_w, WS, s_h, 768, 4, ks, g, bo);

    #pragma unroll
    for (int sb = 0; sb < 16; ++sb)
      #pragma unroll
      for (int j = 0; j < U; ++j) {
        float v = acc[sb][j];
        v += __shfl_xor(v, 1); v += __shfl_xor(v, 2);
        v += __shfl_xor(v, 4); v += __shfl_xor(v, 8);
        acc[sb][j] = v;
      }
    #pragma unroll
    for (int sb = 0; sb < 16; ++sb)
      if (ks == sb) {
        #pragma unroll
        for (int j = 0; j < U; ++j)
          s_gs[(bo * 16 + sb) * 20 + g * U + j] = acc[sb][j];
      }
    __syncthreads();
    for (int idx = tid; idx < B_ * U; idx += NTHR) {
      int b = idx / U, ul = idx - b * U, u = u0 + ul;
      float gi = s_gs[b * 20 + 0 * U + ul] + b1[0 * H_ + u];
      float gf = s_gs[b * 20 + 1 * U + ul] + b1[1 * H_ + u];
      float gg = s_gs[b * 20 + 2 * U + ul] + b1[2 * H_ + u];
      float go = s_gs[b * 20 + 3 * U + ul] + b1[3 * H_ + u];
      float iv = sigmf(gi), fv = sigmf(gf), gv = tanhf(gg), ov = sigmf(go);
      float cn = fv * s_cst[idx] + iv * gv;
      s_cst[idx] = cn;
      cstoreh(h1n + b * H_ + u, ov * tanhf(cn));
    }
    publish(pub + s);
  }
}

// ---------------- Dense head: out(s) = h1(s) @ Wd + bd ----------------
__device__ void run_dense(const float* __restrict__ Wd, const float* __restrict__ bd,
                          const _Float16* __restrict__ h1buf, float* __restrict__ out,
                          int* f1g, int* fD, unsigned char* smem)
{
  const int tid = threadIdx.x;
  _Float16* s_wd = (_Float16*)(smem + SWOFF);   // [4][408] fp16
  for (int idx = tid; idx < 1600; idx += NTHR) {
    int k = idx >> 2, f = idx & 3;
    s_wd[f * 408 + k] = (_Float16)Wd[idx];
  }
  __syncthreads();
  const int b = tid >> 2, kq = tid & 3;
  const int wv = tid >> 6, myg = tid & 7;
  const int t1 = (myg < 1) ? 22 : 21;
  const int kstart = (kq < 2) ? kq * 104 : 208 + (kq - 2) * 96;
  const int nk = (kq < 2) ? 13 : 12;
  const float b0v = bd[0], b1v = bd[1], b2v = bd[2], b3v = bd[3];
  f32x4 r[13];
  for (int s = 0; s < T_; ++s) {
    if (wv == 0) poll8(f1g + myg * 1024 + s, t1);
    __syncthreads();
    const _Float16* hrow = h1buf + (s & 3) * SL + b * H_ + kstart;
    #pragma unroll
    for (int k = 0; k < 13; ++k) {
      const _Float16* p = (k < nk) ? hrow + k * 8 : hrow;
      cload4(r[k], p);
    }
    vwait0();
    __syncthreads();                   // ALL threads' reads of slot s&3 retired
    if (tid == 0) cstorei(fD + s, 1);  // now safe to release the slot
    float a0 = 0.f, a1 = 0.f, a2 = 0.f, a3 = 0.f;
    #pragma unroll
    for (int k = 0; k < 13; ++k) {
      if (k < nk) {
        V4 hv; hv.f = r[k];
        #pragma unroll
        for (int q = 0; q < 4; ++q) {
          h2 hp = hv.h[q];
          int kk = kstart + k * 8 + q * 2;
          a0 = dot2f(hp, *(const h2*)(s_wd + kk), a0);
          a1 = dot2f(hp, *(const h2*)(s_wd + 408 + kk), a1);
          a2 = dot2f(hp, *(const h2*)(s_wd + 816 + kk), a2);
          a3 = dot2f(hp, *(const h2*)(s_wd + 1224 + kk), a3);
        }
      }
    }
    a0 += __shfl_xor(a0, 1); a0 += __shfl_xor(a0, 2);
    a1 += __shfl_xor(a1, 1); a1 += __shfl_xor(a1, 2);
    a2 += __shfl_xor(a2, 1); a2 += __shfl_xor(a2, 2);
    a3 += __shfl_xor(a3, 1); a3 += __shfl_xor(a3, 2);
    float vout = (kq == 0) ? a0 + b0v : (kq == 1) ? a1 + b1v : (kq == 2) ? a2 + b2v : a3 + b3v;
    out[(b * T_ + s) * 4 + kq] = vout;
  }
}

__global__ __launch_bounds__(NTHR, 2) void rnn_kernel(
    const float* __restrict__ xr, const float* __restrict__ xc,
    const float* __restrict__ Wx0, const float* __restrict__ Wh0, const float* __restrict__ b0,
    const float* __restrict__ Wx1, const float* __restrict__ Wh1, const float* __restrict__ b1,
    const float* __restrict__ Wd, const float* __restrict__ bd,
    float* __restrict__ out, float* ws)
{
  __shared__ __align__(16) unsigned char smem[SMEMB];
  const int bid = blockIdx.x;
  int* f0g = (int*)ws;                 // [8][1024]
  int* f1g = f0g + 8192;               // [8][1024]
  int* fD  = f1g + 8192;               // [1024]
  _Float16* h0buf = (_Float16*)(fD + 1024);   // [4][128][400] halfs
  _Float16* h1buf = h0buf + 4 * SL;
  if (bid < G0N) {
    int u0 = bid * H_ / G0N, u1 = (bid + 1) * H_ / G0N;
    if (u1 - u0 == 5) run_l0<5>(bid, u0, xr, xc, Wx0, Wh0, b0, h0buf, f0g, f1g, smem);
    else              run_l0<4>(bid, u0, xr, xc, Wx0, Wh0, b0, h0buf, f0g, f1g, smem);
  } else if (bid < G0N + G1N) {
    int j = bid - G0N;
    int u0 = j * H_ / G1N, u1 = (j + 1) * H_ / G1N;
    if (u1 - u0 == 3) run_l1<3>(j, u0, Wx1, Wh1, b1, h0buf, h1buf, f0g, f1g, fD, smem);
    else              run_l1<2>(j, u0, Wx1, Wh1, b1, h0buf, h1buf, f0g, f1g, fD, smem);
  } else {
    run_dense(Wd, bd, h1buf, out, f1g, fD, smem);
  }
}

extern "C" void kernel_launch(void* const* d_in, const int* in_sizes, int n_in,
                              void* d_out, int out_size, void* d_ws, size_t ws_size,
                              hipStream_t stream) {
  const float* xr  = (const float*)d_in[0];
  const float* xc  = (const float*)d_in[1];
  const float* Wx0 = (const float*)d_in[2];
  const float* Wh0 = (const float*)d_in[3];
  const float* b0  = (const float*)d_in[4];
  const float* Wx1 = (const float*)d_in[5];
  const float* Wh1 = (const float*)d_in[6];
  const float* b1  = (const float*)d_in[7];
  const float* Wd  = (const float*)d_in[8];
  const float* bd  = (const float*)d_in[9];
  float* out = (float*)d_out;
  float* ws  = (float*)d_ws;

  // zero: flag arrays (17408 ints) + slot 3 (the s=-1 state) of h0buf and h1buf
  hipMemsetAsync(d_ws, 0, 69632, stream);
  hipMemsetAsync((char*)d_ws + 69632 + 3 * 102400, 0, 102400, stream);
  hipMemsetAsync((char*)d_ws + 69632 + 409600 + 3 * 102400, 0, 102400, stream);
  hipLaunchKernelGGL(rnn_kernel, dim3(NBLK), dim3(NTHR), 0, stream,
                     xr, xc, Wx0, Wh0, b0, Wx1, Wh1, b1, Wd, bd, out, ws);
}